// Round 1
// baseline (100.908 us; speedup 1.0000x reference)
//
#include <hip/hip_runtime.h>

// FilterAugment: out[b,0,f,t] = features[b,f,t] * 10^(filt_db[b,f]/20)
// filt_db = piecewise-linear interp of band_factors over band_bndry.
// B=64, F=256, T=4096, N_BAND=4. Purely HBM-bound (512 MiB traffic).

constexpr int B_ = 64;
constexpr int F_ = 256;
constexpr int T_ = 4096;
constexpr int NB = 4; // N_BAND

__global__ __launch_bounds__(256) void filter_augment_kernel(
    const float* __restrict__ feat,
    const float* __restrict__ band_factors,  // [B, NB+1]
    const int*   __restrict__ band_bndry,    // [NB+1], bndry[0]=0, bndry[NB]=F
    float* __restrict__ out)
{
    const int row = blockIdx.x;      // b*F + f
    const int b = row >> 8;          // F_ == 256
    const int f = row & (F_ - 1);

    // idx = clip(searchsorted(bndry, f, side='right') - 1, 0, NB-1)
    // = number of interior boundaries (bndry[1..NB-1]) <= f
    int idx = 0;
#pragma unroll
    for (int i = 1; i < NB; ++i) {
        if (band_bndry[i] <= f) idx = i;
    }
    const int lo    = band_bndry[idx];
    const int width = band_bndry[idx + 1] - lo;
    const float t = (width > 1)
        ? (float)(f - lo) / (float)(width - 1)
        : 0.0f;
    const float s = band_factors[b * (NB + 1) + idx];
    const float e = band_factors[b * (NB + 1) + idx + 1];
    const float db = s + (e - s) * t;
    // 10^(db/20) = 2^(db * log2(10)/20)
    const float gain = exp2f(db * 0.16609640474436813f);

    const float4* __restrict__ src = (const float4*)(feat + (size_t)row * T_);
    float4* __restrict__ dst = (float4*)(out + (size_t)row * T_);

    // T/4 = 1024 float4 per row; 256 threads -> 4 iterations
#pragma unroll
    for (int i = 0; i < T_ / 4 / 256; ++i) {
        float4 v = src[threadIdx.x + i * 256];
        v.x *= gain; v.y *= gain; v.z *= gain; v.w *= gain;
        dst[threadIdx.x + i * 256] = v;
    }
}

extern "C" void kernel_launch(void* const* d_in, const int* in_sizes, int n_in,
                              void* d_out, int out_size, void* d_ws, size_t ws_size,
                              hipStream_t stream) {
    const float* feat         = (const float*)d_in[0];
    const float* band_factors = (const float*)d_in[1];
    const int*   band_bndry   = (const int*)d_in[2];
    float* out = (float*)d_out;

    filter_augment_kernel<<<B_ * F_, 256, 0, stream>>>(
        feat, band_factors, band_bndry, out);
}

// Round 3
// 92.144 us; speedup vs baseline: 1.0951x; 1.0951x over previous
//
#include <hip/hip_runtime.h>

// FilterAugment: out[b,0,f,t] = features[b,f,t] * 10^(filt_db[b,f]/20)
// filt_db = piecewise-linear interp of band_factors over band_bndry.
// B=64, F=256, T=4096, N_BAND=4. Purely HBM-bound (537 MB traffic).
// Zero data reuse -> non-temporal loads/stores to bypass cache allocation.
// NOTE: __builtin_nontemporal_* requires a clang NATIVE vector type, not
// HIP_vector_type<float,4> -- use ext_vector_type(4).

typedef float f32x4 __attribute__((ext_vector_type(4)));

constexpr int B_ = 64;
constexpr int F_ = 256;
constexpr int T_ = 4096;
constexpr int NB = 4; // N_BAND

__global__ __launch_bounds__(256) void filter_augment_kernel(
    const float* __restrict__ feat,
    const float* __restrict__ band_factors,  // [B, NB+1]
    const int*   __restrict__ band_bndry,    // [NB+1], bndry[0]=0, bndry[NB]=F
    float* __restrict__ out)
{
    const int row = blockIdx.x;      // b*F + f
    const int b = row >> 8;          // F_ == 256
    const int f = row & (F_ - 1);

    // idx = clip(searchsorted(bndry, f, side='right') - 1, 0, NB-1)
    // = number of interior boundaries (bndry[1..NB-1]) <= f
    int idx = 0;
#pragma unroll
    for (int i = 1; i < NB; ++i) {
        if (band_bndry[i] <= f) idx = i;
    }
    const int lo    = band_bndry[idx];
    const int width = band_bndry[idx + 1] - lo;
    const float t = (width > 1)
        ? (float)(f - lo) / (float)(width - 1)
        : 0.0f;
    const float s = band_factors[b * (NB + 1) + idx];
    const float e = band_factors[b * (NB + 1) + idx + 1];
    const float db = s + (e - s) * t;
    // 10^(db/20) = 2^(db * log2(10)/20)
    const float gain = exp2f(db * 0.16609640474436813f);

    const f32x4* __restrict__ src = (const f32x4*)(feat + (size_t)row * T_);
    f32x4* __restrict__ dst = (f32x4*)(out + (size_t)row * T_);

    // T/4 = 1024 float4 per row; 256 threads -> 4 iterations
#pragma unroll
    for (int i = 0; i < T_ / 4 / 256; ++i) {
        f32x4 v = __builtin_nontemporal_load(&src[threadIdx.x + i * 256]);
        v *= gain;
        __builtin_nontemporal_store(v, &dst[threadIdx.x + i * 256]);
    }
}

extern "C" void kernel_launch(void* const* d_in, const int* in_sizes, int n_in,
                              void* d_out, int out_size, void* d_ws, size_t ws_size,
                              hipStream_t stream) {
    const float* feat         = (const float*)d_in[0];
    const float* band_factors = (const float*)d_in[1];
    const int*   band_bndry   = (const int*)d_in[2];
    float* out = (float*)d_out;

    filter_augment_kernel<<<B_ * F_, 256, 0, stream>>>(
        feat, band_factors, band_bndry, out);
}

// Round 4
// 90.754 us; speedup vs baseline: 1.1119x; 1.0153x over previous
//
#include <hip/hip_runtime.h>

// FilterAugment: out[b,0,f,t] = features[b,f,t] * 10^(filt_db[b,f]/20)
// filt_db = piecewise-linear interp of band_factors over band_bndry.
// B=64, F=256, T=4096, N_BAND=4. Purely HBM-bound (537 MB traffic).
// Zero data reuse -> non-temporal loads/stores bypass cache allocation.
// 2 rows/block, 8 float4/thread: batch all 8 NT loads into registers,
// then all 8 NT stores -> deeper read bursts, fewer blocks (prologue amort).

typedef float f32x4 __attribute__((ext_vector_type(4)));

constexpr int B_ = 64;
constexpr int F_ = 256;
constexpr int T_ = 4096;
constexpr int NB = 4; // N_BAND

__device__ __forceinline__ float row_gain(
    const float* __restrict__ band_factors,
    const int*   __restrict__ band_bndry,
    int b, int f)
{
    // idx = clip(searchsorted(bndry, f, side='right') - 1, 0, NB-1)
    int idx = 0;
#pragma unroll
    for (int i = 1; i < NB; ++i) {
        if (band_bndry[i] <= f) idx = i;
    }
    const int lo    = band_bndry[idx];
    const int width = band_bndry[idx + 1] - lo;
    const float t = (width > 1)
        ? (float)(f - lo) / (float)(width - 1)
        : 0.0f;
    const float s = band_factors[b * (NB + 1) + idx];
    const float e = band_factors[b * (NB + 1) + idx + 1];
    const float db = s + (e - s) * t;
    // 10^(db/20) = 2^(db * log2(10)/20)
    return exp2f(db * 0.16609640474436813f);
}

__global__ __launch_bounds__(256) void filter_augment_kernel(
    const float* __restrict__ feat,
    const float* __restrict__ band_factors,  // [B, NB+1]
    const int*   __restrict__ band_bndry,    // [NB+1]
    float* __restrict__ out)
{
    const int row0 = blockIdx.x * 2;         // two rows per block
    const int b  = row0 >> 8;                // F_ == 256, rows pair within b
    const int f0 = row0 & (F_ - 1);
    const int f1 = f0 + 1;

    const float g0 = row_gain(band_factors, band_bndry, b, f0);
    const float g1 = row_gain(band_factors, band_bndry, b, f1);

    const f32x4* __restrict__ s0 = (const f32x4*)(feat + (size_t)row0 * T_);
    f32x4* __restrict__ d0 = (f32x4*)(out + (size_t)row0 * T_);
    // row1 is contiguous after row0: offset T_/4 float4s

    // Per row: 1024 float4; 256 threads -> 4 float4/row/thread; 8 total.
    f32x4 v[8];
#pragma unroll
    for (int i = 0; i < 4; ++i)
        v[i] = __builtin_nontemporal_load(&s0[threadIdx.x + i * 256]);
#pragma unroll
    for (int i = 0; i < 4; ++i)
        v[4 + i] = __builtin_nontemporal_load(&s0[T_ / 4 + threadIdx.x + i * 256]);

#pragma unroll
    for (int i = 0; i < 4; ++i) {
        v[i] *= g0;
        __builtin_nontemporal_store(v[i], &d0[threadIdx.x + i * 256]);
    }
#pragma unroll
    for (int i = 0; i < 4; ++i) {
        v[4 + i] *= g1;
        __builtin_nontemporal_store(v[4 + i], &d0[T_ / 4 + threadIdx.x + i * 256]);
    }
}

extern "C" void kernel_launch(void* const* d_in, const int* in_sizes, int n_in,
                              void* d_out, int out_size, void* d_ws, size_t ws_size,
                              hipStream_t stream) {
    const float* feat         = (const float*)d_in[0];
    const float* band_factors = (const float*)d_in[1];
    const int*   band_bndry   = (const int*)d_in[2];
    float* out = (float*)d_out;

    filter_augment_kernel<<<B_ * F_ / 2, 256, 0, stream>>>(
        feat, band_factors, band_bndry, out);
}